// Round 1
// baseline (4266.247 us; speedup 1.0000x reference)
//
#include <hip/hip_runtime.h>
#include <math.h>

#define DD 128

// ---------------------------------------------------------------------------
// Scatter: for each edge e: agg_b[dst[e]] += A[src[e]] (raw), agg_a[src[e]] +=
// B[dst[e]] (raw), cnt++. agg is combined [n_a+n_b][128] living in d_out.
// 32 lanes per edge, one float4 per lane.
// ---------------------------------------------------------------------------
__global__ __launch_bounds__(256) void scatter_kernel(
    const float* __restrict__ rows_a, const float* __restrict__ rows_b,
    const int* __restrict__ src, const int* __restrict__ dst,
    float* __restrict__ agg, float* __restrict__ cnt, int n_a, int E)
{
  int gid = blockIdx.x * 256 + threadIdx.x;
  int e = gid >> 5;
  if (e >= E) return;
  int c = (gid & 31) << 2;
  int sa = src[e];
  int db = dst[e];
  float4 fa = *(const float4*)(rows_a + (size_t)sa * DD + c);
  float4 fb = *(const float4*)(rows_b + (size_t)db * DD + c);
  float* pb = agg + ((size_t)(n_a + db)) * DD + c;
  float* pa = agg + (size_t)sa * DD + c;
  atomicAdd(pb + 0, fa.x); atomicAdd(pb + 1, fa.y);
  atomicAdd(pb + 2, fa.z); atomicAdd(pb + 3, fa.w);
  atomicAdd(pa + 0, fb.x); atomicAdd(pa + 1, fb.y);
  atomicAdd(pa + 2, fb.z); atomicAdd(pa + 3, fb.w);
  if ((gid & 31) == 0) {
    atomicAdd(cnt + sa, 1.0f);
    atomicAdd(cnt + n_a + db, 1.0f);
  }
}

// ---------------------------------------------------------------------------
// mean_out[r] = (agg[r]/max(cnt[r],1)) @ W^T + bias   (or 0 if cnt[r]==0)
// W is [128][128] row-major; msg[j] = sum_k x[k]*W[j][k] + b[j].
// Block: 256 threads = 8 rows x 32 col-groups (4 cols each). W^T staged in LDS
// with stride 132 (pad) for conflict-free b128 reads.
// ---------------------------------------------------------------------------
__global__ __launch_bounds__(256) void msg_transform_kernel(
    const float* __restrict__ agg, const float* __restrict__ cnt,
    const float* __restrict__ W, const float* __restrict__ bias,
    float* __restrict__ mean_out, int nrows)
{
  __shared__ float Wt[DD * 132];     // Wt[k*132 + j] = W[j][k]
  __shared__ float xs[8 * DD];
  const int t = threadIdx.x;
  for (int idx = t; idx < DD * DD; idx += 256) {
    int j = idx >> 7, k = idx & (DD - 1);
    Wt[k * 132 + j] = W[idx];
  }
  const int lane = t & 31;
  const int rsub = t >> 5;
  const int j0 = lane << 2;
  const float4 bj = *(const float4*)(bias + j0);
  __syncthreads();
  const int ntiles = (nrows + 7) >> 3;
  for (int tile = blockIdx.x; tile < ntiles; tile += gridDim.x) {
    int r = tile * 8 + rsub;
    bool valid = r < nrows;
    float cv = valid ? cnt[r] : 0.f;
    float inv = 1.f / fmaxf(cv, 1.f);
    float4 av = make_float4(0.f, 0.f, 0.f, 0.f);
    if (valid) av = *(const float4*)(agg + (size_t)r * DD + j0);
    __syncthreads();
    *(float4*)(xs + rsub * DD + j0) =
        make_float4(av.x * inv, av.y * inv, av.z * inv, av.w * inv);
    __syncthreads();
    float4 acc = bj;
    #pragma unroll
    for (int k = 0; k < DD; k += 4) {
      float4 xk = *(const float4*)(xs + rsub * DD + k);
      float4 w0 = *(const float4*)(Wt + (k + 0) * 132 + j0);
      float4 w1 = *(const float4*)(Wt + (k + 1) * 132 + j0);
      float4 w2 = *(const float4*)(Wt + (k + 2) * 132 + j0);
      float4 w3 = *(const float4*)(Wt + (k + 3) * 132 + j0);
      acc.x += xk.x * w0.x; acc.y += xk.x * w0.y; acc.z += xk.x * w0.z; acc.w += xk.x * w0.w;
      acc.x += xk.y * w1.x; acc.y += xk.y * w1.y; acc.z += xk.y * w1.z; acc.w += xk.y * w1.w;
      acc.x += xk.z * w2.x; acc.y += xk.z * w2.y; acc.z += xk.z * w2.z; acc.w += xk.z * w2.w;
      acc.x += xk.w * w3.x; acc.y += xk.w * w3.y; acc.z += xk.w * w3.z; acc.w += xk.w * w3.w;
    }
    if (valid) {
      if (cv < 0.5f) acc = make_float4(0.f, 0.f, 0.f, 0.f);  // cnt==0 -> mean 0
      *(float4*)(mean_out + (size_t)r * DD + j0) = acc;
    }
  }
}

// ---------------------------------------------------------------------------
// out[r] = g*row + (1-g)*mean, g = sigmoid(concat(row,mean) @ Wg^T + bg).
// Wg is [128][256] row-major. Wg^T staged in LDS [256][132]. out aliases agg
// (read during staging of mean? no -- mean comes from mean_ws; out write is
// the only touch of agg here, and it is per-row exclusive).
// ---------------------------------------------------------------------------
__global__ __launch_bounds__(256) void fuse_kernel(
    const float* __restrict__ rows_a, const float* __restrict__ rows_b,
    const float* __restrict__ Wg, const float* __restrict__ bg,
    const float* __restrict__ mean_all, float* __restrict__ out,
    int n_a, int n_total)
{
  __shared__ float Wt[2 * DD * 132];   // [k<256][j<128 +pad]
  __shared__ float xs[8 * 2 * DD];     // 8 rows x 256
  const int t = threadIdx.x;
  for (int idx = t; idx < DD * 2 * DD; idx += 256) {
    int j = idx >> 8;        // row of Wg (output j), row length 256
    int k = idx & 255;
    Wt[k * 132 + j] = Wg[idx];
  }
  const int lane = t & 31;
  const int rsub = t >> 5;
  const int j0 = lane << 2;
  const float4 bj = *(const float4*)(bg + j0);
  __syncthreads();
  const int ntiles = (n_total + 7) >> 3;
  for (int tile = blockIdx.x; tile < ntiles; tile += gridDim.x) {
    int r = tile * 8 + rsub;
    bool valid = r < n_total;
    float4 rv = make_float4(0.f, 0.f, 0.f, 0.f);
    float4 mv = make_float4(0.f, 0.f, 0.f, 0.f);
    if (valid) {
      const float* rowsrc = (r < n_a) ? rows_a + (size_t)r * DD
                                      : rows_b + (size_t)(r - n_a) * DD;
      rv = *(const float4*)(rowsrc + j0);
      mv = *(const float4*)(mean_all + (size_t)r * DD + j0);
    }
    __syncthreads();
    *(float4*)(xs + rsub * 256 + j0) = rv;
    *(float4*)(xs + rsub * 256 + DD + j0) = mv;
    __syncthreads();
    float4 acc = bj;
    #pragma unroll
    for (int k = 0; k < 2 * DD; k += 4) {
      float4 xk = *(const float4*)(xs + rsub * 256 + k);
      float4 w0 = *(const float4*)(Wt + (k + 0) * 132 + j0);
      float4 w1 = *(const float4*)(Wt + (k + 1) * 132 + j0);
      float4 w2 = *(const float4*)(Wt + (k + 2) * 132 + j0);
      float4 w3 = *(const float4*)(Wt + (k + 3) * 132 + j0);
      acc.x += xk.x * w0.x; acc.y += xk.x * w0.y; acc.z += xk.x * w0.z; acc.w += xk.x * w0.w;
      acc.x += xk.y * w1.x; acc.y += xk.y * w1.y; acc.z += xk.y * w1.z; acc.w += xk.y * w1.w;
      acc.x += xk.z * w2.x; acc.y += xk.z * w2.y; acc.z += xk.z * w2.z; acc.w += xk.z * w2.w;
      acc.x += xk.w * w3.x; acc.y += xk.w * w3.y; acc.z += xk.w * w3.z; acc.w += xk.w * w3.w;
    }
    if (valid) {
      float4 g;
      g.x = 1.f / (1.f + __expf(-acc.x));
      g.y = 1.f / (1.f + __expf(-acc.y));
      g.z = 1.f / (1.f + __expf(-acc.z));
      g.w = 1.f / (1.f + __expf(-acc.w));
      float4 o;
      o.x = g.x * rv.x + (1.f - g.x) * mv.x;
      o.y = g.y * rv.y + (1.f - g.y) * mv.y;
      o.z = g.z * rv.z + (1.f - g.z) * mv.z;
      o.w = g.w * rv.w + (1.f - g.w) * mv.w;
      *(float4*)(out + (size_t)r * DD + j0) = o;
    }
  }
}

extern "C" void kernel_launch(void* const* d_in, const int* in_sizes, int n_in,
                              void* d_out, int out_size, void* d_ws, size_t ws_size,
                              hipStream_t stream) {
  const float* A      = (const float*)d_in[0];
  const float* B      = (const float*)d_in[1];
  const float* W_fwd  = (const float*)d_in[2];
  const float* b_fwd  = (const float*)d_in[3];
  const float* W_rev  = (const float*)d_in[4];
  const float* b_rev  = (const float*)d_in[5];
  const float* W_gate = (const float*)d_in[6];
  const float* b_gate = (const float*)d_in[7];
  const int*   src    = (const int*)d_in[8];
  const int*   dst    = (const int*)d_in[9];

  const int n_a = in_sizes[0] / DD;
  const int n_b = in_sizes[1] / DD;
  const int E   = in_sizes[8];
  const int n_total = n_a + n_b;

  float* out     = (float*)d_out;                     // agg (then final output)
  float* mean_ws = (float*)d_ws;                      // [n_total][128]
  float* cnt     = mean_ws + (size_t)n_total * DD;    // [n_total]

  // zero aggregation targets (harness does not re-zero between replays)
  hipMemsetAsync(out, 0, (size_t)n_total * DD * sizeof(float), stream);
  hipMemsetAsync(cnt, 0, (size_t)n_total * sizeof(float), stream);

  // raw scatter-add of rows + counts
  int nblk_scatter = (E * 32 + 255) / 256;
  scatter_kernel<<<nblk_scatter, 256, 0, stream>>>(A, B, src, dst, out, cnt, n_a, E);

  // mean_msg = (agg/cnt) @ W^T + b  (A-range uses W_rev, B-range uses W_fwd)
  msg_transform_kernel<<<1024, 256, 0, stream>>>(out, cnt, W_rev, b_rev,
                                                 mean_ws, n_a);
  msg_transform_kernel<<<1024, 256, 0, stream>>>(out + (size_t)n_a * DD, cnt + n_a,
                                                 W_fwd, b_fwd,
                                                 mean_ws + (size_t)n_a * DD, n_b);

  // gated fusion, writes final output in place over agg
  fuse_kernel<<<1024, 256, 0, stream>>>(A, B, W_gate, b_gate, mean_ws, out,
                                        n_a, n_total);
}

// Round 2
// 1140.586 us; speedup vs baseline: 3.7404x; 3.7404x over previous
//
#include <hip/hip_runtime.h>
#include <math.h>

#define DD 128
#define SCHUNK 2048

// ---------------------------------------------------------------------------
// Phase 1: degree histogram (combined A-range [0,n_a) and B-range [n_a,n_total))
// ---------------------------------------------------------------------------
__global__ __launch_bounds__(256) void hist_kernel(
    const int* __restrict__ src, const int* __restrict__ dst,
    int* __restrict__ cnt, int n_a, int E)
{
  int e = blockIdx.x * 256 + threadIdx.x;
  if (e >= E) return;
  atomicAdd(&cnt[src[e]], 1);
  atomicAdd(&cnt[n_a + dst[e]], 1);
}

// ---------------------------------------------------------------------------
// Phase 2: exclusive scan of cnt[n] -> start[n] (and cursor copy).
// 3-kernel scan: per-chunk sums, single-block scan of partials, final.
// ---------------------------------------------------------------------------
__global__ __launch_bounds__(256) void scan1_kernel(
    const int* __restrict__ cnt, int n, int* __restrict__ partials)
{
  __shared__ int sd[256];
  int t = threadIdx.x;
  int base = blockIdx.x * SCHUNK;
  int s = 0;
  #pragma unroll
  for (int k = 0; k < 8; ++k) {
    int i = base + t * 8 + k;
    s += (i < n) ? cnt[i] : 0;
  }
  sd[t] = s;
  __syncthreads();
  for (int off = 128; off > 0; off >>= 1) {
    if (t < off) sd[t] += sd[t + off];
    __syncthreads();
  }
  if (t == 0) partials[blockIdx.x] = sd[0];
}

__global__ __launch_bounds__(256) void scan2_kernel(int* __restrict__ partials, int nch)
{
  __shared__ int buf[256];
  int t = threadIdx.x;
  int v = (t < nch) ? partials[t] : 0;
  buf[t] = v;
  __syncthreads();
  for (int off = 1; off < 256; off <<= 1) {
    int x = (t >= off) ? buf[t - off] : 0;
    __syncthreads();
    buf[t] += x;
    __syncthreads();
  }
  if (t < nch) partials[t] = buf[t] - v;   // exclusive
}

__global__ __launch_bounds__(256) void scan3_kernel(
    const int* __restrict__ cnt, int n, const int* __restrict__ partials,
    int* __restrict__ start, int* __restrict__ cursor)
{
  __shared__ int sd[256];
  int t = threadIdx.x;
  int base = blockIdx.x * SCHUNK;
  int loc[8];
  int s = 0;
  #pragma unroll
  for (int k = 0; k < 8; ++k) {
    int i = base + t * 8 + k;
    loc[k] = (i < n) ? cnt[i] : 0;
    s += loc[k];
  }
  sd[t] = s;
  __syncthreads();
  for (int off = 1; off < 256; off <<= 1) {
    int x = (t >= off) ? sd[t - off] : 0;
    __syncthreads();
    sd[t] += x;
    __syncthreads();
  }
  int off = partials[blockIdx.x] + sd[t] - s;   // chunk offset + thread-exclusive
  #pragma unroll
  for (int k = 0; k < 8; ++k) {
    int i = base + t * 8 + k;
    if (i < n) { start[i] = off; cursor[i] = off; }
    off += loc[k];
  }
}

// ---------------------------------------------------------------------------
// Phase 3: scatter partner indices into buckets. partner[pos in A-row bucket]
// = B-row index, and vice versa. 2E int atomics total.
// ---------------------------------------------------------------------------
__global__ __launch_bounds__(256) void scatter_ids_kernel(
    const int* __restrict__ src, const int* __restrict__ dst,
    int* __restrict__ cursor, int* __restrict__ partner, int n_a, int E)
{
  int e = blockIdx.x * 256 + threadIdx.x;
  if (e >= E) return;
  int s = src[e], d = dst[e];
  int p = atomicAdd(&cursor[s], 1);
  partner[p] = d;
  int q = atomicAdd(&cursor[n_a + d], 1);
  partner[q] = s;
}

// ---------------------------------------------------------------------------
// Phase 4: one wave (64 lanes) per output row: gather partner rows, register-
// accumulate (2 f32/lane), write mean once. No float atomics.
// ---------------------------------------------------------------------------
__global__ __launch_bounds__(256) void aggregate_mean_kernel(
    const float* __restrict__ rows_a, const float* __restrict__ rows_b,
    const int* __restrict__ partner, const int* __restrict__ start,
    const int* __restrict__ cnt, float* __restrict__ mean_out,
    int n_a, int n_total)
{
  int wid = (blockIdx.x * 256 + threadIdx.x) >> 6;
  if (wid >= n_total) return;
  int lane = threadIdx.x & 63;
  int s0 = start[wid], c = cnt[wid];
  const float* tbl = (wid < n_a) ? rows_b : rows_a;
  float ax = 0.f, ay = 0.f;
  int i = 0;
  for (; i + 4 <= c; i += 4) {
    int p0 = partner[s0 + i + 0];
    int p1 = partner[s0 + i + 1];
    int p2 = partner[s0 + i + 2];
    int p3 = partner[s0 + i + 3];
    float2 v0 = *((const float2*)(tbl + (size_t)p0 * DD) + lane);
    float2 v1 = *((const float2*)(tbl + (size_t)p1 * DD) + lane);
    float2 v2 = *((const float2*)(tbl + (size_t)p2 * DD) + lane);
    float2 v3 = *((const float2*)(tbl + (size_t)p3 * DD) + lane);
    ax += v0.x + v1.x + v2.x + v3.x;
    ay += v0.y + v1.y + v2.y + v3.y;
  }
  for (; i < c; ++i) {
    int p = partner[s0 + i];
    float2 v = *((const float2*)(tbl + (size_t)p * DD) + lane);
    ax += v.x;
    ay += v.y;
  }
  float inv = (c > 0) ? (1.f / (float)c) : 0.f;
  ((float2*)(mean_out + (size_t)wid * DD))[lane] = make_float2(ax * inv, ay * inv);
}

// ---------------------------------------------------------------------------
// Phase 5: in-place per-row linear: data[r] = data[r] @ W^T + b (0 if cnt==0).
// Block: 256 threads = 8 rows x 32 col-groups. W^T staged in LDS (pad 132).
// ---------------------------------------------------------------------------
__global__ __launch_bounds__(256) void msg_transform_inplace_kernel(
    float* __restrict__ data, const int* __restrict__ cnt,
    const float* __restrict__ W, const float* __restrict__ bias, int nrows)
{
  __shared__ float Wt[DD * 132];     // Wt[k*132 + j] = W[j][k]
  __shared__ float xs[8 * DD];
  const int t = threadIdx.x;
  for (int idx = t; idx < DD * DD; idx += 256) {
    int j = idx >> 7, k = idx & (DD - 1);
    Wt[k * 132 + j] = W[idx];
  }
  const int lane = t & 31;
  const int rsub = t >> 5;
  const int j0 = lane << 2;
  const float4 bj = *(const float4*)(bias + j0);
  __syncthreads();
  const int ntiles = (nrows + 7) >> 3;
  for (int tile = blockIdx.x; tile < ntiles; tile += gridDim.x) {
    int r = tile * 8 + rsub;
    bool valid = r < nrows;
    int cv = valid ? cnt[r] : 0;
    float4 av = make_float4(0.f, 0.f, 0.f, 0.f);
    if (valid) av = *(const float4*)(data + (size_t)r * DD + j0);
    __syncthreads();
    *(float4*)(xs + rsub * DD + j0) = av;
    __syncthreads();
    float4 acc = bj;
    #pragma unroll
    for (int k = 0; k < DD; k += 4) {
      float4 xk = *(const float4*)(xs + rsub * DD + k);
      float4 w0 = *(const float4*)(Wt + (k + 0) * 132 + j0);
      float4 w1 = *(const float4*)(Wt + (k + 1) * 132 + j0);
      float4 w2 = *(const float4*)(Wt + (k + 2) * 132 + j0);
      float4 w3 = *(const float4*)(Wt + (k + 3) * 132 + j0);
      acc.x += xk.x * w0.x; acc.y += xk.x * w0.y; acc.z += xk.x * w0.z; acc.w += xk.x * w0.w;
      acc.x += xk.y * w1.x; acc.y += xk.y * w1.y; acc.z += xk.y * w1.z; acc.w += xk.y * w1.w;
      acc.x += xk.z * w2.x; acc.y += xk.z * w2.y; acc.z += xk.z * w2.z; acc.w += xk.z * w2.w;
      acc.x += xk.w * w3.x; acc.y += xk.w * w3.y; acc.z += xk.w * w3.z; acc.w += xk.w * w3.w;
    }
    if (valid) {
      if (cv == 0) acc = make_float4(0.f, 0.f, 0.f, 0.f);  // cnt==0 -> mean_msg 0
      *(float4*)(data + (size_t)r * DD + j0) = acc;
    }
  }
}

// ---------------------------------------------------------------------------
// Phase 6: gated fuse, in place on io (io holds transformed mean, becomes out).
// ---------------------------------------------------------------------------
__global__ __launch_bounds__(256) void fuse_kernel(
    const float* __restrict__ rows_a, const float* __restrict__ rows_b,
    const float* __restrict__ Wg, const float* __restrict__ bg,
    float* __restrict__ io, int n_a, int n_total)
{
  __shared__ float Wt[2 * DD * 132];   // [k<256][j<128 +pad]
  __shared__ float xs[8 * 2 * DD];     // 8 rows x 256
  const int t = threadIdx.x;
  for (int idx = t; idx < DD * 2 * DD; idx += 256) {
    int j = idx >> 8;        // output j; Wg row length 256
    int k = idx & 255;
    Wt[k * 132 + j] = Wg[idx];
  }
  const int lane = t & 31;
  const int rsub = t >> 5;
  const int j0 = lane << 2;
  const float4 bj = *(const float4*)(bg + j0);
  __syncthreads();
  const int ntiles = (n_total + 7) >> 3;
  for (int tile = blockIdx.x; tile < ntiles; tile += gridDim.x) {
    int r = tile * 8 + rsub;
    bool valid = r < n_total;
    float4 rv = make_float4(0.f, 0.f, 0.f, 0.f);
    float4 mv = make_float4(0.f, 0.f, 0.f, 0.f);
    if (valid) {
      const float* rowsrc = (r < n_a) ? rows_a + (size_t)r * DD
                                      : rows_b + (size_t)(r - n_a) * DD;
      rv = *(const float4*)(rowsrc + j0);
      mv = *(const float4*)(io + (size_t)r * DD + j0);
    }
    __syncthreads();
    *(float4*)(xs + rsub * 256 + j0) = rv;
    *(float4*)(xs + rsub * 256 + DD + j0) = mv;
    __syncthreads();
    float4 acc = bj;
    #pragma unroll
    for (int k = 0; k < 2 * DD; k += 4) {
      float4 xk = *(const float4*)(xs + rsub * 256 + k);
      float4 w0 = *(const float4*)(Wt + (k + 0) * 132 + j0);
      float4 w1 = *(const float4*)(Wt + (k + 1) * 132 + j0);
      float4 w2 = *(const float4*)(Wt + (k + 2) * 132 + j0);
      float4 w3 = *(const float4*)(Wt + (k + 3) * 132 + j0);
      acc.x += xk.x * w0.x; acc.y += xk.x * w0.y; acc.z += xk.x * w0.z; acc.w += xk.x * w0.w;
      acc.x += xk.y * w1.x; acc.y += xk.y * w1.y; acc.z += xk.y * w1.z; acc.w += xk.y * w1.w;
      acc.x += xk.z * w2.x; acc.y += xk.z * w2.y; acc.z += xk.z * w2.z; acc.w += xk.z * w2.w;
      acc.x += xk.w * w3.x; acc.y += xk.w * w3.y; acc.z += xk.w * w3.z; acc.w += xk.w * w3.w;
    }
    if (valid) {
      float4 g;
      g.x = 1.f / (1.f + __expf(-acc.x));
      g.y = 1.f / (1.f + __expf(-acc.y));
      g.z = 1.f / (1.f + __expf(-acc.z));
      g.w = 1.f / (1.f + __expf(-acc.w));
      float4 o;
      o.x = g.x * rv.x + (1.f - g.x) * mv.x;
      o.y = g.y * rv.y + (1.f - g.y) * mv.y;
      o.z = g.z * rv.z + (1.f - g.z) * mv.z;
      o.w = g.w * rv.w + (1.f - g.w) * mv.w;
      *(float4*)(io + (size_t)r * DD + j0) = o;
    }
  }
}

extern "C" void kernel_launch(void* const* d_in, const int* in_sizes, int n_in,
                              void* d_out, int out_size, void* d_ws, size_t ws_size,
                              hipStream_t stream) {
  const float* A      = (const float*)d_in[0];
  const float* B      = (const float*)d_in[1];
  const float* W_fwd  = (const float*)d_in[2];
  const float* b_fwd  = (const float*)d_in[3];
  const float* W_rev  = (const float*)d_in[4];
  const float* b_rev  = (const float*)d_in[5];
  const float* W_gate = (const float*)d_in[6];
  const float* b_gate = (const float*)d_in[7];
  const int*   src    = (const int*)d_in[8];
  const int*   dst    = (const int*)d_in[9];

  const int n_a = in_sizes[0] / DD;
  const int n_b = in_sizes[1] / DD;
  const int E   = in_sizes[8];
  const int n_total = n_a + n_b;

  float* out = (float*)d_out;            // mean -> transformed mean -> final out

  // workspace layout (ints)
  int* cnt      = (int*)d_ws;            // [n_total]
  int* start    = cnt + n_total;         // [n_total]
  int* cursor   = start + n_total;       // [n_total]
  int* partials = cursor + n_total;      // [<=1024]
  int* partner  = partials + 1024;       // [2E]

  const int nch = (n_total + SCHUNK - 1) / SCHUNK;
  const int eblk = (E + 255) / 256;

  hipMemsetAsync(cnt, 0, (size_t)n_total * sizeof(int), stream);

  hist_kernel<<<eblk, 256, 0, stream>>>(src, dst, cnt, n_a, E);
  scan1_kernel<<<nch, 256, 0, stream>>>(cnt, n_total, partials);
  scan2_kernel<<<1, 256, 0, stream>>>(partials, nch);
  scan3_kernel<<<nch, 256, 0, stream>>>(cnt, n_total, partials, start, cursor);
  scatter_ids_kernel<<<eblk, 256, 0, stream>>>(src, dst, cursor, partner, n_a, E);

  aggregate_mean_kernel<<<(n_total + 3) / 4, 256, 0, stream>>>(
      A, B, partner, start, cnt, out, n_a, n_total);

  // per-relation linear on the mean (A-range: W_rev, B-range: W_fwd), in place
  msg_transform_inplace_kernel<<<1024, 256, 0, stream>>>(out, cnt, W_rev, b_rev, n_a);
  msg_transform_inplace_kernel<<<1024, 256, 0, stream>>>(
      out + (size_t)n_a * DD, cnt + n_a, W_fwd, b_fwd, n_b);

  // gated fusion, in place
  fuse_kernel<<<1024, 256, 0, stream>>>(A, B, W_gate, b_gate, out, n_a, n_total);
}

// Round 3
// 575.616 us; speedup vs baseline: 7.4116x; 1.9815x over previous
//
#include <hip/hip_runtime.h>
#include <math.h>

#define DD 128
#define SCHUNK 2048

typedef __attribute__((ext_vector_type(8))) short short8;
typedef __attribute__((ext_vector_type(4))) float f32x4;

__device__ __forceinline__ unsigned short f2bf(float f) {
  unsigned int u = __builtin_bit_cast(unsigned int, f);
  u = (u + 0x7FFFu + ((u >> 16) & 1u)) >> 16;   // RNE (finite inputs)
  return (unsigned short)u;
}

__device__ __forceinline__ short8 pack8(float4 a, float4 b) {
  short8 r;
  r[0] = (short)f2bf(a.x); r[1] = (short)f2bf(a.y);
  r[2] = (short)f2bf(a.z); r[3] = (short)f2bf(a.w);
  r[4] = (short)f2bf(b.x); r[5] = (short)f2bf(b.y);
  r[6] = (short)f2bf(b.z); r[7] = (short)f2bf(b.w);
  return r;
}

// ---------------------------------------------------------------------------
// Phase 1: degree histogram
// ---------------------------------------------------------------------------
__global__ __launch_bounds__(256) void hist_kernel(
    const int* __restrict__ src, const int* __restrict__ dst,
    int* __restrict__ cnt, int n_a, int E)
{
  int e = blockIdx.x * 256 + threadIdx.x;
  if (e >= E) return;
  atomicAdd(&cnt[src[e]], 1);
  atomicAdd(&cnt[n_a + dst[e]], 1);
}

// ---------------------------------------------------------------------------
// Phase 2: exclusive scan (3 kernels)
// ---------------------------------------------------------------------------
__global__ __launch_bounds__(256) void scan1_kernel(
    const int* __restrict__ cnt, int n, int* __restrict__ partials)
{
  __shared__ int sd[256];
  int t = threadIdx.x;
  int base = blockIdx.x * SCHUNK;
  int s = 0;
  #pragma unroll
  for (int k = 0; k < 8; ++k) {
    int i = base + t * 8 + k;
    s += (i < n) ? cnt[i] : 0;
  }
  sd[t] = s;
  __syncthreads();
  for (int off = 128; off > 0; off >>= 1) {
    if (t < off) sd[t] += sd[t + off];
    __syncthreads();
  }
  if (t == 0) partials[blockIdx.x] = sd[0];
}

__global__ __launch_bounds__(256) void scan2_kernel(int* __restrict__ partials, int nch)
{
  __shared__ int buf[256];
  int t = threadIdx.x;
  int v = (t < nch) ? partials[t] : 0;
  buf[t] = v;
  __syncthreads();
  for (int off = 1; off < 256; off <<= 1) {
    int x = (t >= off) ? buf[t - off] : 0;
    __syncthreads();
    buf[t] += x;
    __syncthreads();
  }
  if (t < nch) partials[t] = buf[t] - v;   // exclusive
}

__global__ __launch_bounds__(256) void scan3_kernel(
    const int* __restrict__ cnt, int n, const int* __restrict__ partials,
    int* __restrict__ start, int* __restrict__ cursor)
{
  __shared__ int sd[256];
  int t = threadIdx.x;
  int base = blockIdx.x * SCHUNK;
  int loc[8];
  int s = 0;
  #pragma unroll
  for (int k = 0; k < 8; ++k) {
    int i = base + t * 8 + k;
    loc[k] = (i < n) ? cnt[i] : 0;
    s += loc[k];
  }
  sd[t] = s;
  __syncthreads();
  for (int off = 1; off < 256; off <<= 1) {
    int x = (t >= off) ? sd[t - off] : 0;
    __syncthreads();
    sd[t] += x;
    __syncthreads();
  }
  int off = partials[blockIdx.x] + sd[t] - s;
  #pragma unroll
  for (int k = 0; k < 8; ++k) {
    int i = base + t * 8 + k;
    if (i < n) { start[i] = off; cursor[i] = off; }
    off += loc[k];
  }
}

// ---------------------------------------------------------------------------
// Phase 3: scatter partner ids
// ---------------------------------------------------------------------------
__global__ __launch_bounds__(256) void scatter_ids_kernel(
    const int* __restrict__ src, const int* __restrict__ dst,
    int* __restrict__ cursor, int* __restrict__ partner, int n_a, int E)
{
  int e = blockIdx.x * 256 + threadIdx.x;
  if (e >= E) return;
  int s = src[e], d = dst[e];
  int p = atomicAdd(&cursor[s], 1);
  partner[p] = d;
  int q = atomicAdd(&cursor[n_a + d], 1);
  partner[q] = s;
}

// ---------------------------------------------------------------------------
// Phase 4: one wave per row: gather partner rows, mean into mean_out (f32).
// ---------------------------------------------------------------------------
__global__ __launch_bounds__(256) void aggregate_mean_kernel(
    const float* __restrict__ rows_a, const float* __restrict__ rows_b,
    const int* __restrict__ partner, const int* __restrict__ start,
    const int* __restrict__ cnt, float* __restrict__ mean_out,
    int n_a, int n_total)
{
  int wid = (blockIdx.x * 256 + threadIdx.x) >> 6;
  if (wid >= n_total) return;
  int lane = threadIdx.x & 63;
  int s0 = start[wid], c = cnt[wid];
  const float* tbl = (wid < n_a) ? rows_b : rows_a;
  float ax = 0.f, ay = 0.f;
  int i = 0;
  for (; i + 4 <= c; i += 4) {
    int p0 = partner[s0 + i + 0];
    int p1 = partner[s0 + i + 1];
    int p2 = partner[s0 + i + 2];
    int p3 = partner[s0 + i + 3];
    float2 v0 = *((const float2*)(tbl + (size_t)p0 * DD) + lane);
    float2 v1 = *((const float2*)(tbl + (size_t)p1 * DD) + lane);
    float2 v2 = *((const float2*)(tbl + (size_t)p2 * DD) + lane);
    float2 v3 = *((const float2*)(tbl + (size_t)p3 * DD) + lane);
    ax += v0.x + v1.x + v2.x + v3.x;
    ay += v0.y + v1.y + v2.y + v3.y;
  }
  for (; i < c; ++i) {
    int p = partner[s0 + i];
    float2 v = *((const float2*)(tbl + (size_t)p * DD) + lane);
    ax += v.x;
    ay += v.y;
  }
  float inv = (c > 0) ? (1.f / (float)c) : 0.f;
  ((float2*)(mean_out + (size_t)wid * DD))[lane] = make_float2(ax * inv, ay * inv);
}

// ---------------------------------------------------------------------------
// Weight conversion f32 -> bf16 (row-major): [Wrev | Wfwd | Wgate]
// ---------------------------------------------------------------------------
__global__ __launch_bounds__(256) void wconv_kernel(
    const float* __restrict__ Wrev, const float* __restrict__ Wfwd,
    const float* __restrict__ Wgate, unsigned short* __restrict__ dst)
{
  int i = blockIdx.x * 256 + threadIdx.x;   // 65536 total
  float v;
  if (i < 16384) v = Wrev[i];
  else if (i < 32768) v = Wfwd[i - 16384];
  else v = Wgate[i - 32768];
  dst[i] = f2bf(v);
}

// ---------------------------------------------------------------------------
// Phase 5+6 fused (MFMA): per range,
//   t = (cnt>0) ? mean @ Wr^T + br : 0
//   u = row @ Wg[:, :128]^T + t @ Wg[:, 128:]^T + bg
//   out = sigmoid(u) * row + (1 - sigmoid(u)) * t
// 512 threads = 8 waves, 16 rows/wave, 128 rows/block.
// Weights in LDS (bf16) with per-row 16B-octet XOR swizzle; per-wave LDS
// patch relayouts t (C/D layout) into A-fragments.
// mean and out may alias (same rows, dataflow-ordered).
// ---------------------------------------------------------------------------
__global__ __launch_bounds__(512) void fused_post_kernel(
    const float* __restrict__ rowsT, const float* __restrict__ mean,
    const int* __restrict__ cnt, const unsigned short* __restrict__ Wr_bf,
    const unsigned short* __restrict__ Wg_bf, const float* __restrict__ br,
    const float* __restrict__ bg, float* __restrict__ out, int n)
{
  __shared__ unsigned short Wr_l[128 * 128];   // 32 KB
  __shared__ unsigned short Wg_l[128 * 256];   // 64 KB
  __shared__ float br_l[128];
  __shared__ float bg_l[128];
  __shared__ unsigned short t_l[8][16 * 128];  // 32 KB, per-wave patches

  const int t = threadIdx.x;
  // stage Wr (2048 16B-octets), swizzle octet index by (row & 15)
  for (int oi = t; oi < 2048; oi += 512) {
    int j = oi >> 4, o = oi & 15;
    *(short8*)&Wr_l[j * 128 + ((o ^ (j & 15)) << 3)] =
        *(const short8*)&Wr_bf[oi << 3];
  }
  // stage Wg (4096 octets)
  for (int oi = t; oi < 4096; oi += 512) {
    int j = oi >> 5, o = oi & 31;
    *(short8*)&Wg_l[j * 256 + ((o ^ (j & 15)) << 3)] =
        *(const short8*)&Wg_bf[oi << 3];
  }
  if (t < 128) { br_l[t] = br[t]; bg_l[t] = bg[t]; }
  __syncthreads();

  const int wid  = t >> 6;
  const int lane = t & 63;
  const int lrow = lane & 15;   // A/B fragment: row/col index
  const int lgrp = lane >> 4;   // k-octet group
  const int m0 = blockIdx.x * 128 + wid * 16;
  if (m0 >= n) return;

  const int mr = m0 + lrow;
  const bool rowok = mr < n;

  // A-fragments of mean (f32 -> bf16)
  short8 am[4];
  #pragma unroll
  for (int ks = 0; ks < 4; ++ks) {
    int k0 = ks * 32 + lgrp * 8;
    float4 u0 = make_float4(0.f, 0.f, 0.f, 0.f), u1 = u0;
    if (rowok) {
      u0 = *(const float4*)(mean + (size_t)mr * DD + k0);
      u1 = *(const float4*)(mean + (size_t)mr * DD + k0 + 4);
    }
    am[ks] = pack8(u0, u1);
  }

  // t = mean @ Wr^T + br
  f32x4 tac[8];
  #pragma unroll
  for (int jt = 0; jt < 8; ++jt) {
    float bv = br_l[jt * 16 + lrow];
    f32x4 c = {bv, bv, bv, bv};
    #pragma unroll
    for (int ks = 0; ks < 4; ++ks) {
      int o = ks * 4 + lgrp;
      short8 b = *(short8*)&Wr_l[(jt * 16 + lrow) * 128 + ((o ^ lrow) << 3)];
      c = __builtin_amdgcn_mfma_f32_16x16x32_bf16(am[ks], b, c, 0, 0, 0);
    }
    tac[jt] = c;
  }

  // cnt==0 -> t = 0 (mean_msg is exactly 0 in reference, bias included)
  const int rbase = m0 + lgrp * 4;
  #pragma unroll
  for (int r = 0; r < 4; ++r) {
    int rr = rbase + r;
    int cv = (rr < n) ? cnt[rr] : 0;
    if (cv == 0) {
      #pragma unroll
      for (int jt = 0; jt < 8; ++jt) tac[jt][r] = 0.f;
    }
  }

  // relayout t: C/D layout -> per-wave LDS patch (bf16, octet-swizzled)
  unsigned short* tw = t_l[wid];
  #pragma unroll
  for (int jt = 0; jt < 8; ++jt) {
    int col = jt * 16 + lrow;
    int oc = col >> 3, ci = col & 7;
    #pragma unroll
    for (int r = 0; r < 4; ++r) {
      int rr = lgrp * 4 + r;
      tw[rr * 128 + ((oc ^ rr) << 3) + ci] = f2bf(tac[jt][r]);
    }
  }

  // A-fragments of row
  short8 ar[4];
  #pragma unroll
  for (int ks = 0; ks < 4; ++ks) {
    int k0 = ks * 32 + lgrp * 8;
    float4 u0 = make_float4(0.f, 0.f, 0.f, 0.f), u1 = u0;
    if (rowok) {
      u0 = *(const float4*)(rowsT + (size_t)mr * DD + k0);
      u1 = *(const float4*)(rowsT + (size_t)mr * DD + k0 + 4);
    }
    ar[ks] = pack8(u0, u1);
  }

  // A-fragments of t (from the per-wave patch; same-wave, compiler waits lgkm)
  short8 at[4];
  #pragma unroll
  for (int ks = 0; ks < 4; ++ks) {
    int o = ks * 4 + lgrp;
    at[ks] = *(short8*)&tw[lrow * 128 + ((o ^ lrow) << 3)];
  }

  // gate GEMM (K=256) + blend + store
  #pragma unroll
  for (int jt = 0; jt < 8; ++jt) {
    float bv = bg_l[jt * 16 + lrow];
    f32x4 c = {bv, bv, bv, bv};
    #pragma unroll
    for (int ks = 0; ks < 4; ++ks) {
      int o = ks * 4 + lgrp;
      short8 b = *(short8*)&Wg_l[(jt * 16 + lrow) * 256 + ((o ^ lrow) << 3)];
      c = __builtin_amdgcn_mfma_f32_16x16x32_bf16(ar[ks], b, c, 0, 0, 0);
    }
    #pragma unroll
    for (int ks = 0; ks < 4; ++ks) {
      int o = (ks + 4) * 4 + lgrp;
      short8 b = *(short8*)&Wg_l[(jt * 16 + lrow) * 256 + ((o ^ lrow) << 3)];
      c = __builtin_amdgcn_mfma_f32_16x16x32_bf16(at[ks], b, c, 0, 0, 0);
    }
    int col = jt * 16 + lrow;
    #pragma unroll
    for (int r = 0; r < 4; ++r) {
      int rr = rbase + r;
      if (rr < n) {
        float g = 1.f / (1.f + __expf(-c[r]));
        float rowf = rowsT[(size_t)rr * DD + col];
        out[(size_t)rr * DD + col] = g * rowf + (1.f - g) * tac[jt][r];
      }
    }
  }
}

extern "C" void kernel_launch(void* const* d_in, const int* in_sizes, int n_in,
                              void* d_out, int out_size, void* d_ws, size_t ws_size,
                              hipStream_t stream) {
  const float* A      = (const float*)d_in[0];
  const float* B      = (const float*)d_in[1];
  const float* W_fwd  = (const float*)d_in[2];
  const float* b_fwd  = (const float*)d_in[3];
  const float* W_rev  = (const float*)d_in[4];
  const float* b_rev  = (const float*)d_in[5];
  const float* W_gate = (const float*)d_in[6];
  const float* b_gate = (const float*)d_in[7];
  const int*   src    = (const int*)d_in[8];
  const int*   dst    = (const int*)d_in[9];

  const int n_a = in_sizes[0] / DD;
  const int n_b = in_sizes[1] / DD;
  const int E   = in_sizes[8];
  const int n_total = n_a + n_b;

  float* out = (float*)d_out;            // mean -> final out (in place)

  // workspace layout
  int* cnt      = (int*)d_ws;            // [n_total]
  int* start    = cnt + n_total;         // [n_total]
  int* cursor   = start + n_total;       // [n_total]
  int* partials = cursor + n_total;      // [1024]
  int* partner  = partials + 1024;       // [2E]
  uintptr_t wp = (uintptr_t)(partner + 2 * (size_t)E);
  wp = (wp + 63) & ~(uintptr_t)63;
  unsigned short* wbf = (unsigned short*)wp;  // [65536] bf16 weights

  const int nch = (n_total + SCHUNK - 1) / SCHUNK;
  const int eblk = (E + 255) / 256;

  hipMemsetAsync(cnt, 0, (size_t)n_total * sizeof(int), stream);

  hist_kernel<<<eblk, 256, 0, stream>>>(src, dst, cnt, n_a, E);
  scan1_kernel<<<nch, 256, 0, stream>>>(cnt, n_total, partials);
  scan2_kernel<<<1, 256, 0, stream>>>(partials, nch);
  scan3_kernel<<<nch, 256, 0, stream>>>(cnt, n_total, partials, start, cursor);
  scatter_ids_kernel<<<eblk, 256, 0, stream>>>(src, dst, cursor, partner, n_a, E);

  wconv_kernel<<<256, 256, 0, stream>>>(W_rev, W_fwd, W_gate, wbf);

  aggregate_mean_kernel<<<(n_total + 3) / 4, 256, 0, stream>>>(
      A, B, partner, start, cnt, out, n_a, n_total);

  // A range: t = mean_a @ W_rev^T + b_rev
  fused_post_kernel<<<(n_a + 127) / 128, 512, 0, stream>>>(
      A, out, cnt, wbf, wbf + 32768, b_rev, b_gate, out, n_a);
  // B range: t = mean_b @ W_fwd^T + b_fwd
  fused_post_kernel<<<(n_b + 127) / 128, 512, 0, stream>>>(
      B, out + (size_t)n_a * DD, cnt + n_a, wbf + 16384, wbf + 32768,
      b_fwd, b_gate, out + (size_t)n_a * DD, n_b);
}